// Round 23
// baseline (50.611 us; speedup 1.0000x reference)
//
#include <hip/hip_runtime.h>
#include <cstdint>

typedef unsigned long long u64;
typedef unsigned int u32;
typedef int i4 __attribute__((ext_vector_type(4), aligned(4)));

// Problem constants (mirroring the reference)
constexpr int VBITS = 12;
constexpr int VOFF  = 1 << (VBITS - 1);   // 2048
constexpr int GBITS = 10;                 // G = 1024

constexpr int GPB = 16;   // groups per block (R21 config, best)
constexpr int WPB = 4;    // waves per block (256 threads)
constexpr int GPW = 4;    // groups per wave

// Butterfly partner exchange, pipe-optimized (R15, proven):
__device__ inline u32 partner_xor(u32 k, int j) {
    switch (j) {
    case 1:  return (u32)__builtin_amdgcn_mov_dpp((int)k, 0xB1, 0xF, 0xF, true); // quad_perm [1,0,3,2]
    case 2:  return (u32)__builtin_amdgcn_mov_dpp((int)k, 0x4E, 0xF, 0xF, true); // quad_perm [2,3,0,1]
    case 4:  return (u32)__builtin_amdgcn_ds_swizzle((int)k, 0x101F);            // xor 4
    case 8:  return (u32)__builtin_amdgcn_ds_swizzle((int)k, 0x201F);            // xor 8
    case 16: return (u32)__builtin_amdgcn_ds_swizzle((int)k, 0x401F);            // xor 16
    default: return (u32)__shfl_xor((int)k, 32, 64);                             // xor 32
    }
}

__device__ inline u32 wave_sort_u32(u32 k, int lane) {
    #pragma unroll
    for (int ks = 2; ks <= 64; ks <<= 1) {
        #pragma unroll
        for (int j = ks >> 1; j >= 1; j >>= 1) {
            u32 other = partner_xor(k, j);
            bool takeMin = ((lane & ks) == 0) == ((lane & j) == 0);
            u32 mn = min(k, other), mx = max(k, other);
            k = takeMin ? mn : mx;
        }
    }
    return k;
}

// TWO independent sorts interleaved step-by-step (R17/R19, proven best).
__device__ inline void wave_sort_u32x2(u32& k0, u32& k1, int lane) {
    #pragma unroll
    for (int ks = 2; ks <= 64; ks <<= 1) {
        #pragma unroll
        for (int j = ks >> 1; j >= 1; j >>= 1) {
            u32 o0 = partner_xor(k0, j);
            u32 o1 = partner_xor(k1, j);
            bool takeMin = ((lane & ks) == 0) == ((lane & j) == 0);
            u32 mn0 = min(k0, o0), mx0 = max(k0, o0);
            u32 mn1 = min(k1, o1), mx1 = max(k1, o1);
            k0 = takeMin ? mn0 : mx0;
            k1 = takeMin ? mn1 : mx1;
        }
    }
}

__device__ inline u64 wave_sort_u64(u64 k, int lane) {
    #pragma unroll
    for (int ks = 2; ks <= 64; ks <<= 1) {
        #pragma unroll
        for (int j = ks >> 1; j >= 1; j >>= 1) {
            u64 other = __shfl_xor(k, j, 64);
            bool takeMin = ((lane & ks) == 0) == ((lane & j) == 0);
            u64 mn = k < other ? k : other;
            u64 mx = k < other ? other : k;
            k = takeMin ? mn : mx;
        }
    }
    return k;
}

__device__ inline u32 lane_push(int dest_lane, u32 src) {
    return (u32)__builtin_amdgcn_ds_permute(dest_lane << 2, (int)src);
}

// Post-sort packing for the fast (u32-key) path (R15, proven).
__device__ inline u32 post_sort_pack(u32 k, int lane, int r0, int r1, int r2,
                                     int gid, u32* __restrict__ arr,
                                     u64* __restrict__ meta) {
    u32 sk = k >> 6;                       // delta24
    u32 pv = __shfl_up(sk, 1, 64);
    int flag = (lane == 0 || sk != pv) ? 1 : 0;
    u64 bal = __ballot(flag);
    int rank = (int)__popcll(bal & ((1ull << lane) - 1ull)) + flag - 1;
    u32 cnt = (u32)__popcll(bal);
    int orig = (int)(k & 63);

    u32 dByRank = lane_push(rank, sk);        // delta of rank==lane
    u32 rByOrig = lane_push(orig, (u32)rank); // rank of point lane
    u32 packed = (dByRank & 0xFFFFFFu) | (rByOrig << 24);

    if (lane == 0)
        meta[gid] = ((u64)((u32)(r0 - 128) & 4095))
                  | ((u64)((u32)(r1 - 128) & 4095) << 12)
                  | ((u64)((u32)(r2 - 128) & 4095) << 24)
                  | ((u64)cnt << 48);
    arr[(size_t)gid * 64 + lane] = packed;
    return cnt;
}

// Single-group path with exact u64 fallback (R15, proven).
__device__ inline u32 process_group_single(const float* __restrict__ q, int lane,
                                           int gid, u32* __restrict__ arr,
                                           u64* __restrict__ meta) {
    int v0 = (int)floorf(q[0] / 0.1f) + VOFF;
    int v1 = (int)floorf(q[1] / 0.1f) + VOFF;
    int v2 = (int)floorf(q[2] / 0.1f) + VOFF;
    int r0 = __shfl(v0, 0, 64), r1 = __shfl(v1, 0, 64), r2 = __shfl(v2, 0, 64);
    int d0 = v0 - r0 + 128, d1 = v1 - r1 + 128, d2 = v2 - r2 + 128;
    bool bad = ((u32)(d0 | d1 | d2) > 255u) || ((u32)(v0 | v1 | v2) > 4095u);

    if (!__any(bad)) {
        u32 k = ((u32)d0 << 22) | ((u32)d1 << 14) | ((u32)d2 << 6) | (u32)lane;
        k = wave_sort_u32(k, lane);
        return post_sort_pack(k, lane, r0, r1, r2, gid, arr, meta);
    } else {
        u64 code = ((u64)(long long)v0 << 24) | ((u64)(long long)v1 << 12)
                 | (u64)(long long)v2;
        u64 k = wave_sort_u64((code << 6) | (u64)lane, lane);
        u64 sk = k >> 6, pv = __shfl_up(sk, 1, 64);
        int flag = (lane == 0 || sk != pv) ? 1 : 0;
        u64 bal = __ballot(flag);
        int rank = (int)__popcll(bal & ((1ull << lane) - 1ull)) + flag - 1;
        u32 cnt = (u32)__popcll(bal);
        int orig = (int)(k & 63);
        u32 rByOrig = lane_push(orig, (u32)rank);
        if (lane == 0) meta[gid] = ((u64)cnt << 48) | (1ull << 56);
        arr[(size_t)gid * 64 + lane] = rByOrig << 24;
        return cnt;
    }
}

// ---------------------------------------------------------------------------
// Kernel 1: build — no LDS staging (R21), paired interleaved sorts (R17).
// ---------------------------------------------------------------------------
__global__ __launch_bounds__(256) void vox_build(
    const float* __restrict__ pred,
    u32* __restrict__ arr,         // [ngroups*64]
    u64* __restrict__ meta,        // [ngroups]
    u32* __restrict__ blockSums,   // [nblocks]
    int ngroups)
{
    __shared__ u32 s_ws[WPB];
    const int t = threadIdx.x, w = t >> 6, lane = t & 63, b = blockIdx.x;

    u32 wsum = 0;
    for (int jp = 0; jp < GPW; jp += 2) {
        int gid0 = b * GPB + w * GPW + jp, gid1 = gid0 + 1;

        if (gid1 < ngroups) {
            const float* q0 = pred + (size_t)gid0 * 192 + lane * 3;
            const float* q1 = q0 + 192;

            // voxelize both groups (exactly as reference: f32 IEEE divide)
            int a0 = (int)floorf(q0[0] / 0.1f) + VOFF;
            int a1 = (int)floorf(q0[1] / 0.1f) + VOFF;
            int a2 = (int)floorf(q0[2] / 0.1f) + VOFF;
            int c0 = (int)floorf(q1[0] / 0.1f) + VOFF;
            int c1 = (int)floorf(q1[1] / 0.1f) + VOFF;
            int c2 = (int)floorf(q1[2] / 0.1f) + VOFF;

            int ra0 = __shfl(a0, 0, 64), ra1 = __shfl(a1, 0, 64), ra2 = __shfl(a2, 0, 64);
            int rc0 = __shfl(c0, 0, 64), rc1 = __shfl(c1, 0, 64), rc2 = __shfl(c2, 0, 64);
            int da0 = a0 - ra0 + 128, da1 = a1 - ra1 + 128, da2 = a2 - ra2 + 128;
            int dc0 = c0 - rc0 + 128, dc1 = c1 - rc1 + 128, dc2 = c2 - rc2 + 128;
            bool bad0 = ((u32)(da0 | da1 | da2) > 255u) || ((u32)(a0 | a1 | a2) > 4095u);
            bool bad1 = ((u32)(dc0 | dc1 | dc2) > 255u) || ((u32)(c0 | c1 | c2) > 4095u);

            if (!__any(bad0 || bad1)) {
                u32 k0 = ((u32)da0 << 22) | ((u32)da1 << 14) | ((u32)da2 << 6) | (u32)lane;
                u32 k1 = ((u32)dc0 << 22) | ((u32)dc1 << 14) | ((u32)dc2 << 6) | (u32)lane;
                wave_sort_u32x2(k0, k1, lane);
                wsum += post_sort_pack(k0, lane, ra0, ra1, ra2, gid0, arr, meta);
                wsum += post_sort_pack(k1, lane, rc0, rc1, rc2, gid1, arr, meta);
            } else {
                wsum += process_group_single(q0, lane, gid0, arr, meta);
                wsum += process_group_single(q1, lane, gid1, arr, meta);
            }
        } else if (gid0 < ngroups) {
            const float* q0 = pred + (size_t)gid0 * 192 + lane * 3;
            wsum += process_group_single(q0, lane, gid0, arr, meta);
        }
    }
    if (lane == 0) s_ws[w] = wsum;
    __syncthreads();
    if (t == 0) blockSums[b] = s_ws[0] + s_ws[1] + s_ws[2] + s_ws[3];
}

// ---------------------------------------------------------------------------
// Kernel 2: emit — two-phase group pipeline (R23): phase 1 stages ALL 4
// groups into 4 per-wave LDS buffers + issues inv writes; ONE fence; phase 2
// issues all 4 dense dwordx4 copy-outs back-to-back (4x outstanding stores,
// 3 fewer compiler barriers than per-group fencing).
// ---------------------------------------------------------------------------
__global__ __launch_bounds__(256) void vox_emit(
    const float* __restrict__ pred,
    const u32* __restrict__ arr,
    const u64* __restrict__ meta,
    const u32* __restrict__ blockSums,
    int* __restrict__ okeys,     // [totalrows * 5] int32
    int* __restrict__ inv,       // [totalrows]     int32
    int ngroups, int totalrows, int nblocks)
{
    __shared__ u32 s_scr[512];               // scan scratch (2 KB)
    __shared__ int s_row[WPB][GPW][340];     // 4 stage buffers per wave (21.8 KB)
    __shared__ u32 s_c[GPB];
    __shared__ u32 s_baseU[2];
    __shared__ int s_tail[5];
    const int t = threadIdx.x, w = t >> 6, lane = t & 63, b = blockIdx.x;

    // batched per-wave loads for all 4 groups
    u32 a[GPW]; u64 m[GPW];
    #pragma unroll
    for (int j = 0; j < GPW; ++j) {
        int gid = b * GPB + w * GPW + j;
        if (gid < ngroups) {
            a[j] = arr[(size_t)gid * 64 + lane];
            m[j] = meta[gid];
        } else { a[j] = 0; m[j] = 0; }
    }

    if (t < GPB) {
        int gid = b * GPB + t;
        s_c[t] = (gid < ngroups) ? (u32)((meta[gid] >> 48) & 127) : 0;
    }

    // redundant scan: below = sum(blockSums[i<b]), all = total U
    {
        u32 below = 0, all = 0;
        for (int i = t; i < nblocks; i += 256) {
            u32 v = blockSums[i];
            all += v;
            if (i < b) below += v;
        }
        __syncthreads();
        s_scr[t] = below; s_scr[256 + t] = all;
        __syncthreads();
        #pragma unroll
        for (int off = 128; off >= 1; off >>= 1) {
            if (t < off) {
                s_scr[t]       += s_scr[t + off];
                s_scr[256 + t] += s_scr[256 + t + off];
            }
            __syncthreads();
        }
        if (t == 0) { s_baseU[0] = s_scr[0]; s_baseU[1] = s_scr[256]; }
        __syncthreads();
    }

    u32 run = s_baseU[0];
    #pragma unroll
    for (int i = 0; i < GPB; i++) if (i < w * GPW) run += s_c[i];

    u32 cnts[GPW], bases[GPW]; bool fb[GPW];
    #pragma unroll
    for (int j = 0; j < GPW; ++j) {
        cnts[j]  = (u32)((m[j] >> 48) & 127);
        bases[j] = run;
        run += cnts[j];
        fb[j] = ((m[j] >> 56) & 1) != 0;
    }

    // ---- phase 1: inv writes + stage all 4 groups (one fence at end) ----
    #pragma unroll
    for (int j = 0; j < GPW; ++j) {
        int gid = b * GPB + w * GPW + j;
        if (gid < ngroups) {   // wave-uniform
            inv[(size_t)gid * 64 + lane] = (int)(bases[j] + (a[j] >> 24));

            const int bb = gid >> GBITS;
            const int gg = gid & ((1 << GBITS) - 1);

            if (!fb[j]) {
                u32 m0 = (u32)m[j] & 4095, m1 = (u32)(m[j] >> 12) & 4095,
                    m2 = (u32)(m[j] >> 24) & 4095;
                u32 d = a[j] & 0xFFFFFFu;      // lane r holds delta24 of rank r
                if ((u32)lane < cnts[j]) {
                    int* row = &s_row[w][j][lane * 5];
                    row[0] = bb;
                    row[1] = gg;
                    row[2] = (int)((m0 + ((d >> 16) & 255u)) & 4095u) - VOFF;
                    row[3] = (int)((m1 + ((d >> 8) & 255u)) & 4095u) - VOFF;
                    row[4] = (int)((m2 + (d & 255u)) & 4095u) - VOFF;
                }
            } else {
                // ---- rare exact path: recompute code, push to lane==rank,
                //      store rows directly (skipped in phase 2) ----
                const float* p = pred + (size_t)gid * 192 + lane * 3;
                long long w0 = (long long)floorf(p[0] / 0.1f) + VOFF;
                long long w1 = (long long)floorf(p[1] / 0.1f) + VOFF;
                long long w2 = (long long)floorf(p[2] / 0.1f) + VOFF;
                u64 code = ((u64)w0 << 24) | ((u64)w1 << 12) | (u64)w2;
                u32 rinv = a[j] >> 24;
                u32 clo = lane_push((int)rinv, (u32)code);
                u32 chi = lane_push((int)rinv, (u32)(code >> 32));
                u64 c = ((u64)chi << 32) | clo;
                if ((u32)lane < cnts[j]) {
                    int* row = okeys + (size_t)(bases[j] + lane) * 5;
                    row[0] = bb; row[1] = gg;
                    row[2] = (int)((c >> 24) & 4095) - VOFF;
                    row[3] = (int)((c >> 12) & 4095) - VOFF;
                    row[4] = (int)(c & 4095) - VOFF;
                }
            }
        }
    }
    // same-wave DS ops are HW-ordered; fence stops compiler reorder
    asm volatile("" ::: "memory");

    // ---- phase 2: all 4 dense copy-outs back-to-back ----
    #pragma unroll
    for (int j = 0; j < GPW; ++j) {
        int gid = b * GPB + w * GPW + j;
        if (gid < ngroups && !fb[j]) {   // wave-uniform
            const int* buf = &s_row[w][j][0];
            int* dst = okeys + (size_t)bases[j] * 5;
            u32 n5 = cnts[j] * 5u, n5r = n5 & ~3u;
            u32 p0 = 4u * (u32)lane;
            if (p0 < n5r) *(i4*)(dst + p0) = *(const i4*)(buf + p0);
            u32 p1 = 256u + 4u * (u32)lane;
            if (p1 < n5r) *(i4*)(dst + p1) = *(const i4*)(buf + p1);
            u32 rem = n5 - n5r;
            if ((u32)lane < rem) dst[n5r + lane] = buf[n5r + lane];
        }
    }

    // tail fill: rows [U, totalrows) replicate the global max row
    if (w == 0) {
        int lg = ngroups - 1;
        const float* p = pred + (size_t)lg * 192 + lane * 3;
        long long w0 = (long long)floorf(p[0] / 0.1f) + VOFF;
        long long w1 = (long long)floorf(p[1] / 0.1f) + VOFF;
        long long w2 = (long long)floorf(p[2] / 0.1f) + VOFF;
        u64 code = ((u64)w0 << 24) | ((u64)w1 << 12) | (u64)w2;
        #pragma unroll
        for (int off = 32; off >= 1; off >>= 1) {
            u64 o = __shfl_xor(code, off, 64);
            code = (o > code) ? o : code;
        }
        if (lane == 0) {
            s_tail[0] = lg >> GBITS;
            s_tail[1] = lg & ((1 << GBITS) - 1);
            s_tail[2] = (int)((code >> 24) & 4095) - VOFF;
            s_tail[3] = (int)((code >> 12) & 4095) - VOFF;
            s_tail[4] = (int)(code & 4095) - VOFF;
        }
    }
    __syncthreads();
    {
        u32 U = s_baseU[1];
        u32 total5 = (u32)totalrows * 5u;
        u32 stride = (u32)gridDim.x * 256u;
        for (u32 e = U * 5u + (u32)b * 256u + (u32)t; e < total5; e += stride)
            okeys[e] = s_tail[e % 5u];
    }
}

extern "C" void kernel_launch(void* const* d_in, const int* in_sizes, int n_in,
                              void* d_out, int out_size, void* d_ws, size_t ws_size,
                              hipStream_t stream)
{
    const float* pred = (const float*)d_in[0];
    // active_mask is all-true by construction -> group n = (b<<10)|g = n
    int ngroups   = in_sizes[1];                  // 65536
    int totalrows = in_sizes[0] / 3;              // N*P = 4194304
    int nblocks   = (ngroups + GPB - 1) / GPB;    // 4096

    int* okeys = (int*)d_out;                     // [totalrows][5] int32
    int* inv   = okeys + (size_t)totalrows * 5;   // [totalrows]    int32

    char* ws = (char*)d_ws;
    u64* meta      = (u64*)ws;                                  // 512 KB
    u32* arr       = (u32*)(meta + ngroups);                    // 16 MB
    u32* blockSums = arr + (size_t)ngroups * 64;                // 16 KB

    vox_build<<<nblocks, 256, 0, stream>>>(pred, arr, meta, blockSums, ngroups);
    vox_emit<<<nblocks, 256, 0, stream>>>(pred, arr, meta, blockSums,
                                          okeys, inv, ngroups, totalrows, nblocks);
}

// Round 24
// 48.014 us; speedup vs baseline: 1.0541x; 1.0541x over previous
//
#include <hip/hip_runtime.h>
#include <cstdint>

typedef unsigned long long u64;
typedef unsigned int u32;
typedef int i4 __attribute__((ext_vector_type(4), aligned(4)));

// Problem constants (mirroring the reference)
constexpr int VBITS = 12;
constexpr int VOFF  = 1 << (VBITS - 1);   // 2048
constexpr int GBITS = 10;                 // G = 1024

constexpr int GPB = 16;   // groups per block (R21 config, best)
constexpr int WPB = 4;    // waves per block (256 threads)
constexpr int GPW = 4;    // groups per wave

// Butterfly partner exchange, pipe-optimized (R15, proven):
__device__ inline u32 partner_xor(u32 k, int j) {
    switch (j) {
    case 1:  return (u32)__builtin_amdgcn_mov_dpp((int)k, 0xB1, 0xF, 0xF, true); // quad_perm [1,0,3,2]
    case 2:  return (u32)__builtin_amdgcn_mov_dpp((int)k, 0x4E, 0xF, 0xF, true); // quad_perm [2,3,0,1]
    case 4:  return (u32)__builtin_amdgcn_ds_swizzle((int)k, 0x101F);            // xor 4
    case 8:  return (u32)__builtin_amdgcn_ds_swizzle((int)k, 0x201F);            // xor 8
    case 16: return (u32)__builtin_amdgcn_ds_swizzle((int)k, 0x401F);            // xor 16
    default: return (u32)__shfl_xor((int)k, 32, 64);                             // xor 32
    }
}

__device__ inline u32 wave_sort_u32(u32 k, int lane) {
    #pragma unroll
    for (int ks = 2; ks <= 64; ks <<= 1) {
        #pragma unroll
        for (int j = ks >> 1; j >= 1; j >>= 1) {
            u32 other = partner_xor(k, j);
            bool takeMin = ((lane & ks) == 0) == ((lane & j) == 0);
            u32 mn = min(k, other), mx = max(k, other);
            k = takeMin ? mn : mx;
        }
    }
    return k;
}

// TWO independent sorts interleaved step-by-step (R17/R19, proven best).
__device__ inline void wave_sort_u32x2(u32& k0, u32& k1, int lane) {
    #pragma unroll
    for (int ks = 2; ks <= 64; ks <<= 1) {
        #pragma unroll
        for (int j = ks >> 1; j >= 1; j >>= 1) {
            u32 o0 = partner_xor(k0, j);
            u32 o1 = partner_xor(k1, j);
            bool takeMin = ((lane & ks) == 0) == ((lane & j) == 0);
            u32 mn0 = min(k0, o0), mx0 = max(k0, o0);
            u32 mn1 = min(k1, o1), mx1 = max(k1, o1);
            k0 = takeMin ? mn0 : mx0;
            k1 = takeMin ? mn1 : mx1;
        }
    }
}

__device__ inline u64 wave_sort_u64(u64 k, int lane) {
    #pragma unroll
    for (int ks = 2; ks <= 64; ks <<= 1) {
        #pragma unroll
        for (int j = ks >> 1; j >= 1; j >>= 1) {
            u64 other = __shfl_xor(k, j, 64);
            bool takeMin = ((lane & ks) == 0) == ((lane & j) == 0);
            u64 mn = k < other ? k : other;
            u64 mx = k < other ? other : k;
            k = takeMin ? mn : mx;
        }
    }
    return k;
}

__device__ inline u32 lane_push(int dest_lane, u32 src) {
    return (u32)__builtin_amdgcn_ds_permute(dest_lane << 2, (int)src);
}

__device__ inline u32 wave_reduce_sum_u32(u32 x) {
    #pragma unroll
    for (int off = 32; off >= 1; off >>= 1) x += __shfl_xor(x, off, 64);
    return x;
}

// Post-sort packing for the fast (u32-key) path (R15, proven).
__device__ inline u32 post_sort_pack(u32 k, int lane, int r0, int r1, int r2,
                                     int gid, u32* __restrict__ arr,
                                     u64* __restrict__ meta) {
    u32 sk = k >> 6;                       // delta24
    u32 pv = __shfl_up(sk, 1, 64);
    int flag = (lane == 0 || sk != pv) ? 1 : 0;
    u64 bal = __ballot(flag);
    int rank = (int)__popcll(bal & ((1ull << lane) - 1ull)) + flag - 1;
    u32 cnt = (u32)__popcll(bal);
    int orig = (int)(k & 63);

    u32 dByRank = lane_push(rank, sk);        // delta of rank==lane
    u32 rByOrig = lane_push(orig, (u32)rank); // rank of point lane
    u32 packed = (dByRank & 0xFFFFFFu) | (rByOrig << 24);

    if (lane == 0)
        meta[gid] = ((u64)((u32)(r0 - 128) & 4095))
                  | ((u64)((u32)(r1 - 128) & 4095) << 12)
                  | ((u64)((u32)(r2 - 128) & 4095) << 24)
                  | ((u64)cnt << 48);
    arr[(size_t)gid * 64 + lane] = packed;
    return cnt;
}

// Single-group path with exact u64 fallback (R15, proven).
__device__ inline u32 process_group_single(const float* __restrict__ q, int lane,
                                           int gid, u32* __restrict__ arr,
                                           u64* __restrict__ meta) {
    int v0 = (int)floorf(q[0] / 0.1f) + VOFF;
    int v1 = (int)floorf(q[1] / 0.1f) + VOFF;
    int v2 = (int)floorf(q[2] / 0.1f) + VOFF;
    int r0 = __shfl(v0, 0, 64), r1 = __shfl(v1, 0, 64), r2 = __shfl(v2, 0, 64);
    int d0 = v0 - r0 + 128, d1 = v1 - r1 + 128, d2 = v2 - r2 + 128;
    bool bad = ((u32)(d0 | d1 | d2) > 255u) || ((u32)(v0 | v1 | v2) > 4095u);

    if (!__any(bad)) {
        u32 k = ((u32)d0 << 22) | ((u32)d1 << 14) | ((u32)d2 << 6) | (u32)lane;
        k = wave_sort_u32(k, lane);
        return post_sort_pack(k, lane, r0, r1, r2, gid, arr, meta);
    } else {
        u64 code = ((u64)(long long)v0 << 24) | ((u64)(long long)v1 << 12)
                 | (u64)(long long)v2;
        u64 k = wave_sort_u64((code << 6) | (u64)lane, lane);
        u64 sk = k >> 6, pv = __shfl_up(sk, 1, 64);
        int flag = (lane == 0 || sk != pv) ? 1 : 0;
        u64 bal = __ballot(flag);
        int rank = (int)__popcll(bal & ((1ull << lane) - 1ull)) + flag - 1;
        u32 cnt = (u32)__popcll(bal);
        int orig = (int)(k & 63);
        u32 rByOrig = lane_push(orig, (u32)rank);
        if (lane == 0) meta[gid] = ((u64)cnt << 48) | (1ull << 56);
        arr[(size_t)gid * 64 + lane] = rByOrig << 24;
        return cnt;
    }
}

// ---------------------------------------------------------------------------
// Kernel 1: build — no LDS staging (R21), paired interleaved sorts (R17).
// ---------------------------------------------------------------------------
__global__ __launch_bounds__(256) void vox_build(
    const float* __restrict__ pred,
    u32* __restrict__ arr,         // [ngroups*64]
    u64* __restrict__ meta,        // [ngroups]
    u32* __restrict__ blockSums,   // [nblocks]
    int ngroups)
{
    __shared__ u32 s_ws[WPB];
    const int t = threadIdx.x, w = t >> 6, lane = t & 63, b = blockIdx.x;

    u32 wsum = 0;
    for (int jp = 0; jp < GPW; jp += 2) {
        int gid0 = b * GPB + w * GPW + jp, gid1 = gid0 + 1;

        if (gid1 < ngroups) {
            const float* q0 = pred + (size_t)gid0 * 192 + lane * 3;
            const float* q1 = q0 + 192;

            // voxelize both groups (exactly as reference: f32 IEEE divide)
            int a0 = (int)floorf(q0[0] / 0.1f) + VOFF;
            int a1 = (int)floorf(q0[1] / 0.1f) + VOFF;
            int a2 = (int)floorf(q0[2] / 0.1f) + VOFF;
            int c0 = (int)floorf(q1[0] / 0.1f) + VOFF;
            int c1 = (int)floorf(q1[1] / 0.1f) + VOFF;
            int c2 = (int)floorf(q1[2] / 0.1f) + VOFF;

            int ra0 = __shfl(a0, 0, 64), ra1 = __shfl(a1, 0, 64), ra2 = __shfl(a2, 0, 64);
            int rc0 = __shfl(c0, 0, 64), rc1 = __shfl(c1, 0, 64), rc2 = __shfl(c2, 0, 64);
            int da0 = a0 - ra0 + 128, da1 = a1 - ra1 + 128, da2 = a2 - ra2 + 128;
            int dc0 = c0 - rc0 + 128, dc1 = c1 - rc1 + 128, dc2 = c2 - rc2 + 128;
            bool bad0 = ((u32)(da0 | da1 | da2) > 255u) || ((u32)(a0 | a1 | a2) > 4095u);
            bool bad1 = ((u32)(dc0 | dc1 | dc2) > 255u) || ((u32)(c0 | c1 | c2) > 4095u);

            if (!__any(bad0 || bad1)) {
                u32 k0 = ((u32)da0 << 22) | ((u32)da1 << 14) | ((u32)da2 << 6) | (u32)lane;
                u32 k1 = ((u32)dc0 << 22) | ((u32)dc1 << 14) | ((u32)dc2 << 6) | (u32)lane;
                wave_sort_u32x2(k0, k1, lane);
                wsum += post_sort_pack(k0, lane, ra0, ra1, ra2, gid0, arr, meta);
                wsum += post_sort_pack(k1, lane, rc0, rc1, rc2, gid1, arr, meta);
            } else {
                wsum += process_group_single(q0, lane, gid0, arr, meta);
                wsum += process_group_single(q1, lane, gid1, arr, meta);
            }
        } else if (gid0 < ngroups) {
            const float* q0 = pred + (size_t)gid0 * 192 + lane * 3;
            wsum += process_group_single(q0, lane, gid0, arr, meta);
        }
    }
    if (lane == 0) s_ws[w] = wsum;
    __syncthreads();
    if (t == 0) blockSums[b] = s_ws[0] + s_ws[1] + s_ws[2] + s_ws[3];
}

// ---------------------------------------------------------------------------
// Kernel 2: emit (R21 body; R24: scan preamble via wave-level shfl reduce —
// 1 barrier instead of 9, 32 B LDS scratch instead of 2 KB).
// ---------------------------------------------------------------------------
__global__ __launch_bounds__(256) void vox_emit(
    const float* __restrict__ pred,
    const u32* __restrict__ arr,
    const u64* __restrict__ meta,
    const u32* __restrict__ blockSums,
    int* __restrict__ okeys,     // [totalrows * 5] int32
    int* __restrict__ inv,       // [totalrows]     int32
    int ngroups, int totalrows, int nblocks)
{
    __shared__ u32 s_wred[2][WPB];        // per-wave partial sums
    __shared__ int s_row[WPB][336];       // per-wave row stage (16B-aligned)
    __shared__ u32 s_c[GPB];
    __shared__ int s_tail[5];
    const int t = threadIdx.x, w = t >> 6, lane = t & 63, b = blockIdx.x;

    // batched per-wave loads for all 4 groups
    u32 a[GPW]; u64 m[GPW];
    #pragma unroll
    for (int j = 0; j < GPW; ++j) {
        int gid = b * GPB + w * GPW + j;
        if (gid < ngroups) {
            a[j] = arr[(size_t)gid * 64 + lane];
            m[j] = meta[gid];
        } else { a[j] = 0; m[j] = 0; }
    }

    if (t < GPB) {
        int gid = b * GPB + t;
        s_c[t] = (gid < ngroups) ? (u32)((meta[gid] >> 48) & 127) : 0;
    }

    // redundant scan: below = sum(blockSums[i<b]), all = total U
    // (wave-level shfl reduction; single barrier)
    {
        u32 below = 0, all = 0;
        for (int i = t; i < nblocks; i += 256) {
            u32 v = blockSums[i];
            all += v;
            if (i < b) below += v;
        }
        below = wave_reduce_sum_u32(below);
        all   = wave_reduce_sum_u32(all);
        if (lane == 0) { s_wred[0][w] = below; s_wred[1][w] = all; }
    }
    __syncthreads();   // s_c and s_wred ready

    const u32 blockBase = s_wred[0][0] + s_wred[0][1] + s_wred[0][2] + s_wred[0][3];
    const u32 totalU    = s_wred[1][0] + s_wred[1][1] + s_wred[1][2] + s_wred[1][3];

    u32 base = blockBase;
    #pragma unroll
    for (int i = 0; i < GPB; i++) if (i < w * GPW) base += s_c[i];

    int* buf = s_row[w];   // this wave's private stage (no cross-wave use)

    #pragma unroll
    for (int j = 0; j < GPW; ++j) {
        int gid = b * GPB + w * GPW + j;
        if (gid < ngroups) {   // wave-uniform
            u32 cnt = (u32)((m[j] >> 48) & 127);
            u32 rinv = a[j] >> 24;

            inv[(size_t)gid * 64 + lane] = (int)(base + rinv);

            const int bb = gid >> GBITS;
            const int gg = gid & ((1 << GBITS) - 1);
            int* dst = okeys + (size_t)base * 5;

            if (!((m[j] >> 56) & 1)) {
                // ---- fast path: stage rows dense in LDS, vector copy-out ----
                u32 m0 = (u32)m[j] & 4095, m1 = (u32)(m[j] >> 12) & 4095,
                    m2 = (u32)(m[j] >> 24) & 4095;
                u32 d = a[j] & 0xFFFFFFu;      // lane r holds delta24 of rank r
                if ((u32)lane < cnt) {
                    int* row = buf + lane * 5;
                    row[0] = bb;
                    row[1] = gg;
                    row[2] = (int)((m0 + ((d >> 16) & 255u)) & 4095u) - VOFF;
                    row[3] = (int)((m1 + ((d >> 8) & 255u)) & 4095u) - VOFF;
                    row[4] = (int)((m2 + (d & 255u)) & 4095u) - VOFF;
                }
                // same-wave DS ops are HW-ordered; fence stops compiler reorder
                asm volatile("" ::: "memory");

                u32 n5 = cnt * 5u, n5r = n5 & ~3u;
                u32 p0 = 4u * (u32)lane;
                if (p0 < n5r) *(i4*)(dst + p0) = *(const i4*)(buf + p0);
                u32 p1 = 256u + 4u * (u32)lane;
                if (p1 < n5r) *(i4*)(dst + p1) = *(const i4*)(buf + p1);
                u32 rem = n5 - n5r;
                if ((u32)lane < rem) dst[n5r + lane] = buf[n5r + lane];
            } else {
                // ---- rare exact path: recompute code, push to lane==rank ----
                const float* p = pred + (size_t)gid * 192 + lane * 3;
                long long w0 = (long long)floorf(p[0] / 0.1f) + VOFF;
                long long w1 = (long long)floorf(p[1] / 0.1f) + VOFF;
                long long w2 = (long long)floorf(p[2] / 0.1f) + VOFF;
                u64 code = ((u64)w0 << 24) | ((u64)w1 << 12) | (u64)w2;
                u32 clo = lane_push((int)rinv, (u32)code);
                u32 chi = lane_push((int)rinv, (u32)(code >> 32));
                u64 c = ((u64)chi << 32) | clo;
                if (lane < (int)cnt) {
                    int* row = dst + (size_t)lane * 5;
                    row[0] = bb; row[1] = gg;
                    row[2] = (int)((c >> 24) & 4095) - VOFF;
                    row[3] = (int)((c >> 12) & 4095) - VOFF;
                    row[4] = (int)(c & 4095) - VOFF;
                }
            }
            base += cnt;
        }
    }

    // tail fill: rows [U, totalrows) replicate the global max row
    if (w == 0) {
        int lg = ngroups - 1;
        const float* p = pred + (size_t)lg * 192 + lane * 3;
        long long w0 = (long long)floorf(p[0] / 0.1f) + VOFF;
        long long w1 = (long long)floorf(p[1] / 0.1f) + VOFF;
        long long w2 = (long long)floorf(p[2] / 0.1f) + VOFF;
        u64 code = ((u64)w0 << 24) | ((u64)w1 << 12) | (u64)w2;
        #pragma unroll
        for (int off = 32; off >= 1; off >>= 1) {
            u64 o = __shfl_xor(code, off, 64);
            code = (o > code) ? o : code;
        }
        if (lane == 0) {
            s_tail[0] = lg >> GBITS;
            s_tail[1] = lg & ((1 << GBITS) - 1);
            s_tail[2] = (int)((code >> 24) & 4095) - VOFF;
            s_tail[3] = (int)((code >> 12) & 4095) - VOFF;
            s_tail[4] = (int)(code & 4095) - VOFF;
        }
    }
    __syncthreads();
    {
        u32 total5 = (u32)totalrows * 5u;
        u32 stride = (u32)gridDim.x * 256u;
        for (u32 e = totalU * 5u + (u32)b * 256u + (u32)t; e < total5; e += stride)
            okeys[e] = s_tail[e % 5u];
    }
}

extern "C" void kernel_launch(void* const* d_in, const int* in_sizes, int n_in,
                              void* d_out, int out_size, void* d_ws, size_t ws_size,
                              hipStream_t stream)
{
    const float* pred = (const float*)d_in[0];
    // active_mask is all-true by construction -> group n = (b<<10)|g = n
    int ngroups   = in_sizes[1];                  // 65536
    int totalrows = in_sizes[0] / 3;              // N*P = 4194304
    int nblocks   = (ngroups + GPB - 1) / GPB;    // 4096

    int* okeys = (int*)d_out;                     // [totalrows][5] int32
    int* inv   = okeys + (size_t)totalrows * 5;   // [totalrows]    int32

    char* ws = (char*)d_ws;
    u64* meta      = (u64*)ws;                                  // 512 KB
    u32* arr       = (u32*)(meta + ngroups);                    // 16 MB
    u32* blockSums = arr + (size_t)ngroups * 64;                // 16 KB

    vox_build<<<nblocks, 256, 0, stream>>>(pred, arr, meta, blockSums, ngroups);
    vox_emit<<<nblocks, 256, 0, stream>>>(pred, arr, meta, blockSums,
                                          okeys, inv, ngroups, totalrows, nblocks);
}